// Round 4
// baseline (211.710 us; speedup 1.0000x reference)
//
#include <hip/hip_runtime.h>
#include <hip/hip_bf16.h>

// Problem constants
#define SRC   16384      // 128*128 source pixels
#define DCH   64         // channels
#define NCLS  19         // classes
#define NPAIR (NCLS*DCH) // 1216 (c,d) pairs
#define NBLK  512        // persistent grid: 2 blocks/CU x 256 CUs (guaranteed co-resident)
#define NITEM (NPAIR*2)  // kde work items: 2 pixel-halves per pair

// Bare v_exp_f32 (args in [-450,0]; underflow->0 matches reference f32 exp).
#if defined(__has_builtin)
#if __has_builtin(__builtin_amdgcn_exp2f)
#define EXP2F(x) __builtin_amdgcn_exp2f(x)
#else
#define EXP2F(x) __builtin_exp2f(x)
#endif
#else
#define EXP2F(x) __builtin_exp2f(x)
#endif

// ---------------------------------------------------------------------------
// Node 1: zero the grid-barrier counter (d_ws is re-poisoned 0xAA each call).
// ---------------------------------------------------------------------------
__global__ void hl_init_kernel(unsigned* __restrict__ bar)
{
    __hip_atomic_store(bar, 0u, __ATOMIC_RELAXED, __HIP_MEMORY_SCOPE_SYSTEM);
}

// Device-scope grid barrier. Correct because all NBLK blocks are co-resident
// (capacity argument: 16 waves/block, 32 waves/CU, VGPR<=64 via launch_bounds,
// LDS < 2 KB). Release: __threadfence (agent-scope wb) before arrive;
// Acquire: __threadfence (inv) after the spin; __syncthreads brackets make it
// block-wide (all waves on the same CU, covered by thread0's cache ops).
__device__ __forceinline__ void grid_barrier(unsigned* bar, unsigned target)
{
    __syncthreads();   // drains this block's outstanding stores (vmcnt(0))
    if (threadIdx.x == 0) {
        __threadfence();
        __hip_atomic_fetch_add(bar, 1u, __ATOMIC_RELAXED, __HIP_MEMORY_SCOPE_AGENT);
        while (__hip_atomic_load(bar, __ATOMIC_RELAXED, __HIP_MEMORY_SCOPE_AGENT) < target)
            __builtin_amdgcn_s_sleep(2);
        __threadfence();
    }
    __syncthreads();
}

// ---------------------------------------------------------------------------
// Node 2: everything, in one persistent kernel.
//   Phase 1  count:   cnt[c*SRC+s] = #subpixels of class c in pixel s's 4x4 block
//   Phase 2  moments: S1/S2 per (c,d), ncls per c       (fp32 partials, f64 reduce)
//   Phase 3  kde:     7-bin Gaussian KDE partials, 2 pixel-halves per pair
//   Phase 4  loss:    normalize, smooth-L1 vs fixed target, mean over active
// ---------------------------------------------------------------------------
__global__ __launch_bounds__(1024, 8) void hl_fused_kernel(
    const float* __restrict__ feature, const int* __restrict__ label,
    unsigned char* __restrict__ cnt,
    double* __restrict__ S1, double* __restrict__ S2, int* __restrict__ ncls,
    float* __restrict__ sample, unsigned* __restrict__ bar,
    float* __restrict__ out)
{
    const int tid = threadIdx.x;
    const int wid = tid >> 6;

    __shared__ double ps1[16], ps2[16];
    __shared__ int    pn[16];
    __shared__ float  part[16][7];
    __shared__ float  sh_mu, sh_istd;
    __shared__ float  lw[16], aw[16];

    // ---------------- Phase 1: per-pixel class counts (blocks 0..15) -------
    if (blockIdx.x < 16) {
        int s  = blockIdx.x * 1024 + tid;          // 0..16383
        int sy = s >> 7, sx = s & 127;
        const int4* lab4 = (const int4*)label;
        int l[16];
#pragma unroll
        for (int r = 0; r < 4; r++) {
            int4 v = lab4[(4 * sy + r) * 128 + sx];
            l[4 * r + 0] = v.x; l[4 * r + 1] = v.y;
            l[4 * r + 2] = v.z; l[4 * r + 3] = v.w;
        }
#pragma unroll
        for (int c = 0; c < NCLS; c++) {
            int cc = 0;
#pragma unroll
            for (int j = 0; j < 16; j++) cc += (l[j] == c) ? 1 : 0;
            cnt[c * SRC + s] = (unsigned char)cc;
        }
    }
    grid_barrier(bar, NBLK);

    // ---------------- Phase 2: moments per (c,d) ---------------------------
    for (int w = blockIdx.x; w < NPAIR; w += NBLK) {
        int c = w >> 6, d = w & 63;
        const float4*       fp4 = (const float4*)(feature + d * SRC);
        const unsigned int* cp4 = (const unsigned int*)(cnt + c * SRC);

        float f1 = 0.f, f2 = 0.f;
        int   nc = 0;
#pragma unroll
        for (int i = 0; i < 4; i++) {
            int g = i * 1024 + tid;                // 4096 float4-groups
            float4       x  = fp4[g];
            unsigned int cv = cp4[g];
            float xs[4] = {x.x, x.y, x.z, x.w};
            float cf[4] = {(float)(cv & 255u), (float)((cv >> 8) & 255u),
                           (float)((cv >> 16) & 255u), (float)(cv >> 24)};
#pragma unroll
            for (int e = 0; e < 4; e++) {
                float wx = cf[e] * xs[e];
                f1 += wx;
                f2 = fmaf(wx, xs[e], f2);
            }
            nc += (cv & 255u) + ((cv >> 8) & 255u) + ((cv >> 16) & 255u) + (cv >> 24);
        }
        double s1 = (double)f1, s2 = (double)f2;
#pragma unroll
        for (int o = 32; o > 0; o >>= 1) {
            s1 += __shfl_down(s1, o);
            s2 += __shfl_down(s2, o);
            nc += __shfl_down(nc, o);
        }
        if ((tid & 63) == 0) { ps1[wid] = s1; ps2[wid] = s2; pn[wid] = nc; }
        __syncthreads();
        if (tid == 0) {
            double a = 0.0, b = 0.0; int n = 0;
#pragma unroll
            for (int i = 0; i < 16; i++) { a += ps1[i]; b += ps2[i]; n += pn[i]; }
            S1[w] = a; S2[w] = b;
            if (d == 0) ncls[c] = n;
        }
        __syncthreads();
    }
    grid_barrier(bar, 2 * NBLK);

    // ---------------- Phase 3: KDE partials (2 halves per pair) ------------
    for (int item = blockIdx.x; item < NITEM; item += NBLK) {
        int w    = item >> 1;
        int half = item & 1;
        int c = w >> 6, d = w & 63;

        if (tid == 0) {
            int    n     = ncls[c];
            double nsafe = (n > 0) ? (double)n : 1.0;
            double s1 = S1[w], s2 = S2[w];
            double mu  = s1 / nsafe;
            double var = (s2 - 2.0 * mu * s1 + mu * mu * (double)n) / nsafe + 1e-10;
            sh_mu   = (float)mu;
            sh_istd = (float)(1.0 / sqrt(var));
        }
        __syncthreads();
        float istd = sh_istd;
        float nm   = -sh_mu * istd;               // u = fma(x, istd, nm)

        const float4*       fp4 = (const float4*)(feature + d * SRC);
        const unsigned int* cp4 = (const unsigned int*)(cnt + c * SRC);

        const float C1 = -18.033688011112042f;    // -12.5 * log2(e)
        float acc[7] = {0.f, 0.f, 0.f, 0.f, 0.f, 0.f, 0.f};

#pragma unroll
        for (int i = 0; i < 2; i++) {
            int g = half * 2048 + i * 1024 + tid; // 2048 float4-groups per half
            float4       x  = fp4[g];
            unsigned int cv = cp4[g];
            float xs[4] = {x.x, x.y, x.z, x.w};
            float cf[4] = {(float)(cv & 255u), (float)((cv >> 8) & 255u),
                           (float)((cv >> 16) & 255u), (float)(cv >> 24)};
#pragma unroll
            for (int e = 0; e < 4; e++) {
                float u = fmaf(xs[e], istd, nm);
                float p = C1 * u;
                float q = p * u;                  // C1*u^2
#pragma unroll
                for (int k = 0; k < 7; k++) {
                    float km  = (float)(k - 3);
                    float arg = fmaf(p, -2.f * km, q + C1 * km * km);
                    acc[k] = fmaf(cf[e], EXP2F(arg), acc[k]);
                }
            }
        }

#pragma unroll
        for (int j = 0; j < 7; j++) {
            float v = acc[j];
#pragma unroll
            for (int o = 32; o > 0; o >>= 1) v += __shfl_down(v, o);
            if ((tid & 63) == 0) part[wid][j] = v;
        }
        __syncthreads();
        if (tid < 7) {
            float v = 0.f;
#pragma unroll
            for (int i = 0; i < 16; i++) v += part[i][tid];
            sample[item * 7 + tid] = v;
        }
        __syncthreads();
    }
    grid_barrier(bar, 3 * NBLK);

    // ---------------- Phase 4: final loss (block 0 only) -------------------
    if (blockIdx.x != 0) return;

    float targ[7];
    {
        double e[7], z = 0.0;
#pragma unroll
        for (int k = -3; k <= 3; k++) { e[k + 3] = exp(-0.5 * (double)(k * k)); z += e[k + 3]; }
#pragma unroll
        for (int j = 0; j < 7; j++) targ[j] = (float)(e[j] / z);
    }

    float lsum = 0.f, asum = 0.f;
    for (int p = tid; p < NPAIR; p += 1024) {
        int c = p >> 6;
        int n = ncls[c];
        if (n < 1000) continue;                   // inactive class
        float sv[7], S = 0.f;
#pragma unroll
        for (int j = 0; j < 7; j++) {
            sv[j] = sample[(2 * p) * 7 + j] + sample[(2 * p + 1) * 7 + j];
            S += sv[j];
        }
        float Ss = fmaxf(S, 1e-30f);
        float ps = 0.f;
#pragma unroll
        for (int j = 0; j < 7; j++) {
            float dd = fabsf(sv[j] / Ss - targ[j]);
            ps += (dd < 1.f) ? 0.5f * dd * dd : (dd - 0.5f);
        }
        lsum += ps;
        if ((p & 63) == 0) asum += 1.f;           // count each active class once
    }
#pragma unroll
    for (int o = 32; o > 0; o >>= 1) {
        lsum += __shfl_down(lsum, o);
        asum += __shfl_down(asum, o);
    }
    if ((tid & 63) == 0) { lw[wid] = lsum; aw[wid] = asum; }
    __syncthreads();
    if (tid == 0) {
        float L = 0.f, A = 0.f;
#pragma unroll
        for (int i = 0; i < 16; i++) { L += lw[i]; A += aw[i]; }
        out[0] = (A > 0.f) ? (L / 448.0f) / A : 0.0f;  // mean over D*7=448, /active
    }
}

// ---------------------------------------------------------------------------
extern "C" void kernel_launch(void* const* d_in, const int* in_sizes, int n_in,
                              void* d_out, int out_size, void* d_ws, size_t ws_size,
                              hipStream_t stream)
{
    const float* feature = (const float*)d_in[0];   // [1,64,128,128] fp32
    const int*   label   = (const int*)d_in[1];     // [1,1,512,512]  int32
    float*       out     = (float*)d_out;           // scalar fp32

    char* ws = (char*)d_ws;
    unsigned char* cnt    = (unsigned char*)(ws);                   // 311296 B
    double*        S1     = (double*)(ws + 311296);                 // 9728 B
    double*        S2     = (double*)(ws + 311296 + 9728);          // 9728 B
    int*           ncls   = (int*)(ws + 311296 + 2 * 9728);         // 76 B (pad 128)
    float*         sample = (float*)(ws + 311296 + 2 * 9728 + 128); // 2432*7*4 = 68096 B
    unsigned*      bar    = (unsigned*)(ws + 399104);               // barrier counter

    hl_init_kernel<<<1, 1, 0, stream>>>(bar);
    hl_fused_kernel<<<NBLK, 1024, 0, stream>>>(feature, label, cnt, S1, S2, ncls,
                                               sample, bar, out);
}

// Round 5
// 110.571 us; speedup vs baseline: 1.9147x; 1.9147x over previous
//
#include <hip/hip_runtime.h>
#include <hip/hip_bf16.h>

// Problem constants
#define SRC    16384     // 128*128 source pixels
#define DCH    64        // channels
#define NCLS   19        // classes
#define NPAIR  (NCLS*DCH)// 1216 (c,d) pairs
#define NCHUNK 256       // stage-A chunks
#define CPX    64        // pixels per chunk (NCHUNK*CPX == SRC)
#define KSPLIT 2         // pixel-split blocks per pair in the KDE kernel

// Bare v_exp_f32 (args in [-450,0]; underflow->0 matches reference f32 exp).
#if defined(__has_builtin)
#if __has_builtin(__builtin_amdgcn_exp2f)
#define EXP2F(x) __builtin_amdgcn_exp2f(x)
#else
#define EXP2F(x) __exp2f(x)
#endif
#else
#define EXP2F(x) __exp2f(x)
#endif

// ---------------------------------------------------------------------------
// K1: per-source-pixel class counts. Each source pixel covers a 4x4 block of
// the 512x512 label map. cnt[c*SRC + s] = #subpixels with label c (0..16).
// ---------------------------------------------------------------------------
__global__ __launch_bounds__(256) void hl_count_kernel(
    const int* __restrict__ label, unsigned char* __restrict__ cnt)
{
    int s  = blockIdx.x * 256 + threadIdx.x;   // 64 blocks x 256 = 16384
    int sy = s >> 7, sx = s & 127;
    const int4* lab4 = (const int4*)label;
    int l[16];
#pragma unroll
    for (int r = 0; r < 4; r++) {
        int4 v = lab4[(4 * sy + r) * 128 + sx];
        l[4 * r + 0] = v.x; l[4 * r + 1] = v.y;
        l[4 * r + 2] = v.z; l[4 * r + 3] = v.w;
    }
#pragma unroll
    for (int c = 0; c < NCLS; c++) {
        int cc = 0;
#pragma unroll
        for (int j = 0; j < 16; j++) cc += (l[j] == c) ? 1 : 0;
        cnt[c * SRC + s] = (unsigned char)cc;
    }
}

// ---------------------------------------------------------------------------
// K2 (stage A): chunked moments partials. Moments are the GEMM
// CNT[19 x 16K] x [X, X^2][16K x 64]. Block = one 64-pixel chunk, 256 thr:
// thread (d = t&63, g = t>>6) holds its 16 x's in registers and accumulates
// a1[c] = sum cv*x, a2[c] = sum cv*x^2 over 19 classes. Feature is read
// exactly once, one 64B line per thread. Cross-wave (g) reduce via LDS in a
// fixed order; also emits per-chunk class pixel-counts PN.
// ---------------------------------------------------------------------------
__global__ __launch_bounds__(256) void hl_stageA_kernel(
    const float* __restrict__ feature, const unsigned char* __restrict__ cnt,
    float* __restrict__ P1, float* __restrict__ P2, int* __restrict__ PN)
{
    int cb = blockIdx.x;            // chunk 0..255
    int t  = threadIdx.x;
    int d  = t & 63, g = t >> 6;    // g = wave id (0..3)
    int s0 = cb * CPX;

    // 16 pixels for this (d, g): one 64B line of channel d
    const float4* f4 = (const float4*)(feature + d * SRC + s0 + 16 * g);
    float xs[16];
#pragma unroll
    for (int i = 0; i < 4; i++) {
        float4 v = f4[i];
        xs[4 * i + 0] = v.x; xs[4 * i + 1] = v.y;
        xs[4 * i + 2] = v.z; xs[4 * i + 3] = v.w;
    }

    float a1[NCLS], a2[NCLS];
#pragma unroll
    for (int c = 0; c < NCLS; c++) {
        const uint4* c4 = (const uint4*)(cnt + c * SRC + s0 + 16 * g);
        uint4 cw = *c4;             // 16 counts (broadcast across d-threads)
        unsigned int wdw[4] = {cw.x, cw.y, cw.z, cw.w};
        float s1 = 0.f, s2 = 0.f;
#pragma unroll
        for (int q = 0; q < 4; q++) {
#pragma unroll
            for (int b = 0; b < 4; b++) {
                float cv = (float)((wdw[q] >> (8 * b)) & 0xFFu);
                float x  = xs[4 * q + b];
                float wx = cv * x;
                s1 += wx;
                s2 = fmaf(wx, x, s2);
            }
        }
        a1[c] = s1; a2[c] = s2;
    }

    // fixed-order cross-wave reduce: wave 0 writes, waves 1..3 add in turn
    __shared__ float b1[NPAIR], b2[NPAIR];
#pragma unroll
    for (int r = 0; r < 4; r++) {
        if (g == r) {
            if (r == 0) {
#pragma unroll
                for (int c = 0; c < NCLS; c++) { b1[c * 64 + d] = a1[c]; b2[c * 64 + d] = a2[c]; }
            } else {
#pragma unroll
                for (int c = 0; c < NCLS; c++) { b1[c * 64 + d] += a1[c]; b2[c * 64 + d] += a2[c]; }
            }
        }
        __syncthreads();
    }
    for (int i = t; i < NPAIR; i += 256) {
        P1[cb * NPAIR + i] = b1[i];
        P2[cb * NPAIR + i] = b2[i];
    }
    // per-chunk class pixel-count (SWAR byte sums of 16 dwords)
    if (t < NCLS) {
        const uint4* cr = (const uint4*)(cnt + t * SRC + s0);
        int n = 0;
#pragma unroll
        for (int i = 0; i < 4; i++) {
            uint4 v = cr[i];
            unsigned int ww[4] = {v.x, v.y, v.z, v.w};
#pragma unroll
            for (int q = 0; q < 4; q++)
                n += (ww[q] & 0xFF) + ((ww[q] >> 8) & 0xFF) + ((ww[q] >> 16) & 0xFF) + (ww[q] >> 24);
        }
        PN[cb * NCLS + t] = n;
    }
}

// ---------------------------------------------------------------------------
// K3 (stage B): reduce the 256 chunk partials per pair in f64 (fixed tree,
// deterministic) -> S1, S2; and ncls[c] from PN.
// ---------------------------------------------------------------------------
__global__ __launch_bounds__(1024) void hl_stageB_kernel(
    const float* __restrict__ P1, const float* __restrict__ P2,
    const int* __restrict__ PN,
    double* __restrict__ S1, double* __restrict__ S2, int* __restrict__ ncls)
{
    int c = blockIdx.x;             // 19 blocks
    int t = threadIdx.x;
    int d = t >> 4, j = t & 15;     // 64 d x 16 j

    double s1 = 0.0, s2 = 0.0;
    for (int ch = j; ch < NCHUNK; ch += 16) {
        s1 += (double)P1[ch * NPAIR + c * 64 + d];
        s2 += (double)P2[ch * NPAIR + c * 64 + d];
    }
#pragma unroll
    for (int o = 8; o > 0; o >>= 1) {   // reduce over j (low 4 lane bits)
        s1 += __shfl_down(s1, o);
        s2 += __shfl_down(s2, o);
    }
    if (j == 0) { S1[c * 64 + d] = s1; S2[c * 64 + d] = s2; }

    __shared__ int nb[4];
    if (t < NCHUNK) {
        int n = PN[t * NCLS + c];
#pragma unroll
        for (int o = 32; o > 0; o >>= 1) n += __shfl_down(n, o);
        if ((t & 63) == 0) nb[t >> 6] = n;
    }
    __syncthreads();
    if (t == 0) ncls[c] = nb[0] + nb[1] + nb[2] + nb[3];
}

// ---------------------------------------------------------------------------
// K4: KDE. KSPLIT blocks per (c,d), each covering SRC/KSPLIT pixels.
// C1*(u-k)^2 = q - 2k*p + C1*k^2 with p = C1*u, q = p*u. Bare v_exp_f32.
// The 1/sqrt(2*pi*var_s) factor cancels in downstream normalization.
// ---------------------------------------------------------------------------
__global__ __launch_bounds__(1024) void hl_kde_kernel(
    const float* __restrict__ feature, const unsigned char* __restrict__ cnt,
    const double* __restrict__ S1d, const double* __restrict__ S2d,
    const int* __restrict__ ncls, float* __restrict__ sample)
{
    int blk  = blockIdx.x;          // 0..NPAIR*KSPLIT-1
    int w    = blk >> 1;            // pair
    int half = blk & 1;
    int c = w >> 6, d = w & 63;
    int tid = threadIdx.x;

    __shared__ float sh_mu, sh_istd;
    if (tid == 0) {
        int    n     = ncls[c];
        double nsafe = (n > 0) ? (double)n : 1.0;
        double s1 = S1d[w], s2 = S2d[w];
        double mu  = s1 / nsafe;
        double var = (s2 - 2.0 * mu * s1 + mu * mu * (double)n) / nsafe + 1e-10;
        sh_mu   = (float)mu;
        sh_istd = (float)(1.0 / sqrt(var));
    }
    __syncthreads();
    float istd = sh_istd;
    float nm   = -sh_mu * istd;     // u = fma(x, istd, nm)

    const float4*       fp4 = (const float4*)(feature + d * SRC);
    const unsigned int* cp4 = (const unsigned int*)(cnt + c * SRC);

    const float C1 = -18.033688011112042f;   // -12.5 * log2(e)
    float acc[7] = {0.f, 0.f, 0.f, 0.f, 0.f, 0.f, 0.f};

#pragma unroll
    for (int i = 0; i < 2; i++) {
        int g = half * 2048 + i * 1024 + tid;   // 2048 float4-groups per half
        float4       x  = fp4[g];
        unsigned int cv = cp4[g];
        float xs[4] = {x.x, x.y, x.z, x.w};
        float cf[4] = {(float)(cv & 255u), (float)((cv >> 8) & 255u),
                       (float)((cv >> 16) & 255u), (float)(cv >> 24)};
#pragma unroll
        for (int e = 0; e < 4; e++) {
            float u = fmaf(xs[e], istd, nm);
            float p = C1 * u;
            float q = p * u;                     // C1*u^2
#pragma unroll
            for (int k = 0; k < 7; k++) {
                float km  = (float)(k - 3);
                float arg = fmaf(p, -2.f * km, q + C1 * km * km);
                acc[k] = fmaf(cf[e], EXP2F(arg), acc[k]);
            }
        }
    }

    __shared__ float part[16][7];
    int wid = tid >> 6;
#pragma unroll
    for (int j = 0; j < 7; j++) {
        float v = acc[j];
#pragma unroll
        for (int o = 32; o > 0; o >>= 1) v += __shfl_down(v, o);
        if ((tid & 63) == 0) part[wid][j] = v;
    }
    __syncthreads();
    if (tid < 7) {
        float v = 0.f;
#pragma unroll
        for (int i = 0; i < 16; i++) v += part[i][tid];
        sample[blk * 7 + tid] = v;
    }
}

// ---------------------------------------------------------------------------
// K5: final loss. Combine KSPLIT partials, normalize, smooth-L1 vs fixed
// target, gate by n>=1000, average over active classes. Single block.
// ---------------------------------------------------------------------------
__global__ __launch_bounds__(512) void hl_loss_kernel(
    const float* __restrict__ sample, const int* __restrict__ ncls,
    float* __restrict__ out)
{
    int tid = threadIdx.x;

    float targ[7];
    {
        double e[7], z = 0.0;
#pragma unroll
        for (int k = -3; k <= 3; k++) { e[k + 3] = exp(-0.5 * (double)(k * k)); z += e[k + 3]; }
#pragma unroll
        for (int j = 0; j < 7; j++) targ[j] = (float)(e[j] / z);
    }

    float lsum = 0.f, asum = 0.f;
    for (int p = tid; p < NPAIR; p += 512) {
        int c = p >> 6;
        int n = ncls[c];
        if (n < 1000) continue;             // inactive class
        float sv[7], S = 0.f;
#pragma unroll
        for (int j = 0; j < 7; j++) {
            sv[j] = sample[(2 * p) * 7 + j] + sample[(2 * p + 1) * 7 + j];
            S += sv[j];
        }
        float Ss = fmaxf(S, 1e-30f);
        float ps = 0.f;
#pragma unroll
        for (int j = 0; j < 7; j++) {
            float dd = fabsf(sv[j] / Ss - targ[j]);
            ps += (dd < 1.f) ? 0.5f * dd * dd : (dd - 0.5f);
        }
        lsum += ps;
        if ((p & 63) == 0) asum += 1.f;     // count each active class once
    }
#pragma unroll
    for (int o = 32; o > 0; o >>= 1) {
        lsum += __shfl_down(lsum, o);
        asum += __shfl_down(asum, o);
    }
    __shared__ float lw[8], aw[8];
    int wid = tid >> 6;
    if ((tid & 63) == 0) { lw[wid] = lsum; aw[wid] = asum; }
    __syncthreads();
    if (tid == 0) {
        float L = 0.f, A = 0.f;
#pragma unroll
        for (int i = 0; i < 8; i++) { L += lw[i]; A += aw[i]; }
        out[0] = (A > 0.f) ? (L / 448.0f) / A : 0.0f;  // mean over D*7=448, /active
    }
}

// ---------------------------------------------------------------------------
extern "C" void kernel_launch(void* const* d_in, const int* in_sizes, int n_in,
                              void* d_out, int out_size, void* d_ws, size_t ws_size,
                              hipStream_t stream)
{
    const float* feature = (const float*)d_in[0];   // [1,64,128,128] fp32
    const int*   label   = (const int*)d_in[1];     // [1,1,512,512]  int32
    float*       out     = (float*)d_out;           // scalar fp32

    char* ws = (char*)d_ws;
    unsigned char* cnt    = (unsigned char*)(ws);                 // 311296 B
    float*         P1     = (float*)(ws + 311296);                // 256*1216*4 = 1245184
    float*         P2     = (float*)(ws + 1556480);               // 1245184
    int*           PN     = (int*)(ws + 2801664);                 // 256*19*4 = 19456
    double*        S1     = (double*)(ws + 2821120);              // 9728
    double*        S2     = (double*)(ws + 2830848);              // 9728
    int*           ncls   = (int*)(ws + 2840576);                 // 76 (pad 128)
    float*         sample = (float*)(ws + 2840704);               // 2432*7*4 = 68096

    hl_count_kernel <<<SRC / 256, 256, 0, stream>>>(label, cnt);
    hl_stageA_kernel<<<NCHUNK, 256, 0, stream>>>(feature, cnt, P1, P2, PN);
    hl_stageB_kernel<<<NCLS, 1024, 0, stream>>>(P1, P2, PN, S1, S2, ncls);
    hl_kde_kernel   <<<NPAIR * KSPLIT, 1024, 0, stream>>>(feature, cnt, S1, S2, ncls, sample);
    hl_loss_kernel  <<<1, 512, 0, stream>>>(sample, ncls, out);
}